// Round 18
// baseline (241.047 us; speedup 1.0000x reference)
//
#include <hip/hip_runtime.h>
#include <hip/hip_bf16.h>

#define DEVINL __device__ __forceinline__

typedef short bf16x8 __attribute__((ext_vector_type(8)));
typedef float f32x4 __attribute__((ext_vector_type(4)));
typedef ushort ushort8v __attribute__((ext_vector_type(8)));

static constexpr int Bn = 8, Ln = 512, DM = 512, DI = 1024, DS = 16, DFF = 2048;
static constexpr int Mtok = Bn * Ln; // 4096
static constexpr int NCH = 32, CLS = 16; // scan chunks, chunk length

DEVINL float bf2f(ushort u) { union { uint i; float f; } v; v.i = uint(u) << 16; return v.f; }
DEVINL ushort f2bf(float f) {
  union { float f; uint i; } v; v.f = f;
  uint r = v.i + 0x7FFF + ((v.i >> 16) & 1);
  return ushort(r >> 16);
}

// Fast hardware exp2 (single v_exp_f32).
#if __has_builtin(__builtin_amdgcn_exp2f)
#define EXP2F(x) __builtin_amdgcn_exp2f(x)
#else
#define EXP2F(x) __expf((x) * 0.69314718056f)
#endif

// async global->LDS, 16B per lane.
#define GLOAD16(gp, lp)                                                        \
  __builtin_amdgcn_global_load_lds(                                            \
      (const __attribute__((address_space(1))) void*)(gp),                     \
      (__attribute__((address_space(3))) void*)(lp), 16, 0, 0)

// ---------------------------------------------------------------------------
// fp32 -> bf16 bulk converter.
// ---------------------------------------------------------------------------
struct CvtJob { const float* src; ushort* dst; int blk0; int _pad; };
struct CvtTab { CvtJob j[11]; };

__global__ __launch_bounds__(256)
void cvt_k(CvtTab tb, int njobs) {
  const int blk = blockIdx.x;
  int ji = 0;
#pragma unroll
  for (int k = 1; k < 11; ++k)
    if (k < njobs && tb.j[k].blk0 <= blk) ji = k;
  const CvtJob J = tb.j[ji];
  const size_t base = (size_t)(blk - J.blk0) * 2048 + (size_t)threadIdx.x * 8;
  float4 a = *(const float4*)(J.src + base);
  float4 b = *(const float4*)(J.src + base + 4);
  ushort8v o;
  o[0] = f2bf(a.x); o[1] = f2bf(a.y); o[2] = f2bf(a.z); o[3] = f2bf(a.w);
  o[4] = f2bf(b.x); o[5] = f2bf(b.y); o[6] = f2bf(b.z); o[7] = f2bf(b.w);
  *(ushort8v*)(J.dst + base) = o;
}

// ---------------------------------------------------------------------------
// m97-structure LDS GEMM: C(M,N) = A(M,K) @ W(N,K)^T, bf16, BK=32, 4 waves.
// EPI: 0 none, 1 bias, 3 bias+fast-gelu. XCD-aware bijective block swizzle
// (requires gridDim.x*gridDim.y % 8 == 0): each XCD gets a contiguous run of
// x-tiles within a y-panel -> W-panel fetched ~once per XCD.
// ---------------------------------------------------------------------------
template<int BM, int BN, int WM, int WN, int EPI, int OUTF32, int DUALK>
__global__ __launch_bounds__(256)
void gemm_lds(const ushort* __restrict__ A0, const ushort* __restrict__ W0,
              void* __restrict__ C0v, const float* __restrict__ bias0,
              const ushort* __restrict__ A1, const ushort* __restrict__ W1,
              void* __restrict__ C1v, const float* __restrict__ bias1,
              const ushort* __restrict__ Ab0, const ushort* __restrict__ Wb0,
              int K, int lda, int ldw, int ldc, int Kb, int ldab, int ldwb)
{
  constexpr int MT = BM / WM / 16, NT = BN / WN / 16;
  constexpr int RA = BM * 32 / 2048, RB = BN * 32 / 2048;
  __shared__ ushort As[BM * 32];
  __shared__ ushort Bs[BN * 32];

  const ushort* Ap = blockIdx.z ? A1 : A0;
  const ushort* Wp = blockIdx.z ? W1 : W0;
  void* Cv         = blockIdx.z ? C1v : C0v;
  const float* bia = blockIdx.z ? bias1 : bias0;

  // XCD-aware bijective swizzle within the x-y plane (per z-problem).
  const int gx = gridDim.x, nwg = gx * gridDim.y;
  const int orig = blockIdx.x + gx * blockIdx.y;
  const int q = nwg >> 3;
  const int work = (orig & 7) * q + (orig >> 3);
  const int bxs = work % gx, bys = work / gx;

  const int tid = threadIdx.x, lane = tid & 63, wv = tid >> 6;
  const int wm = wv / WN, wn = wv % WN;
  const int mbase = bxs * BM, nbase = bys * BN;
  const int r = lane & 15, ko = (lane >> 4) * 8;

  f32x4 acc[MT][NT];
#pragma unroll
  for (int mi = 0; mi < MT; ++mi)
#pragma unroll
    for (int ni = 0; ni < NT; ++ni) acc[mi][ni] = (f32x4){0.f, 0.f, 0.f, 0.f};

  for (int blkK = 0; blkK < (DUALK ? 2 : 1); ++blkK) {
    const ushort* Au = (DUALK && blkK) ? Ab0 : Ap;
    const ushort* Wu = (DUALK && blkK) ? Wb0 : Wp;
    const int Ku  = (DUALK && blkK) ? Kb : K;
    const int ldau = (DUALK && blkK) ? ldab : lda;
    const int ldwu = (DUALK && blkK) ? ldwb : ldw;

    for (int k0 = 0; k0 < Ku; k0 += 32) {
      __syncthreads();
#pragma unroll
      for (int i = 0; i < RA; ++i) {
        const int e = i * 2048 + wv * 512 + lane * 8;
        const int row = e >> 5, ck = e & 31;
        GLOAD16(Au + (size_t)(mbase + row) * ldau + k0 + ck,
                (ushort*)As + i * 2048 + wv * 512);
      }
#pragma unroll
      for (int i = 0; i < RB; ++i) {
        const int e = i * 2048 + wv * 512 + lane * 8;
        const int row = e >> 5, ck = e & 31;
        GLOAD16(Wu + (size_t)(nbase + row) * ldwu + k0 + ck,
                (ushort*)Bs + i * 2048 + wv * 512);
      }
      __syncthreads();

      bf16x8 af[MT], bfv[NT];
#pragma unroll
      for (int mi = 0; mi < MT; ++mi)
        af[mi] = *(const bf16x8*)&As[(wm * MT * 16 + mi * 16 + r) * 32 + ko];
#pragma unroll
      for (int ni = 0; ni < NT; ++ni)
        bfv[ni] = *(const bf16x8*)&Bs[(wn * NT * 16 + ni * 16 + r) * 32 + ko];
#pragma unroll
      for (int mi = 0; mi < MT; ++mi)
#pragma unroll
        for (int ni = 0; ni < NT; ++ni)
          acc[mi][ni] = __builtin_amdgcn_mfma_f32_16x16x32_bf16(af[mi], bfv[ni], acc[mi][ni], 0, 0, 0);
    }
  }

  const int rr = (lane >> 4) * 4, cc = lane & 15;
#pragma unroll
  for (int ni = 0; ni < NT; ++ni) {
    const int col = nbase + wn * NT * 16 + ni * 16 + cc;
    float bsv = 0.f;
    if (EPI >= 1) bsv = bia[col];
#pragma unroll
    for (int mi = 0; mi < MT; ++mi) {
#pragma unroll
      for (int j = 0; j < 4; ++j) {
        const int row = mbase + wm * MT * 16 + mi * 16 + rr + j;
        float v = acc[mi][ni][j] + bsv;
        if (EPI == 3) {
          const float t = v * (0.7978845608f + v * v * 0.0356774081f);
          v = v / (1.f + EXP2F(t * -2.885390082f));
        }
        if (OUTF32) ((float*)Cv)[(size_t)row * ldc + col] = v;
        else        ((ushort*)Cv)[(size_t)row * ldc + col] = f2bf(v);
      }
    }
  }
}

// ---------------------------------------------------------------------------
// Fused xproj + dt projection (see round-16 comments).
// ---------------------------------------------------------------------------
__global__ __launch_bounds__(256)
void xproj_k(const ushort* __restrict__ A0, const ushort* __restrict__ W0,
             ushort* __restrict__ C0,
             const ushort* __restrict__ A1, const ushort* __restrict__ W1,
             ushort* __restrict__ C1,
             const ushort* __restrict__ dtw0, const float* __restrict__ dtb0,
             const ushort* __restrict__ dtw1, const float* __restrict__ dtb1,
             ushort* __restrict__ db0, ushort* __restrict__ db1)
{
  const ushort* A   = blockIdx.z ? A1 : A0;
  const ushort* W   = blockIdx.z ? W1 : W0;
  ushort* C         = blockIdx.z ? C1 : C0;
  const ushort* dtw = blockIdx.z ? dtw1 : dtw0;
  const float*  dtb = blockIdx.z ? dtb1 : dtb0;
  ushort* db        = blockIdx.z ? db1 : db0;

  __shared__ ushort dt_lds[16][32];

  const int tid = threadIdx.x, lane = tid & 63, wv = tid >> 6;
  const int r = lane & 15, ko = (lane >> 4) * 8;
  const int mbase = blockIdx.x * 16;
  const int nbase = wv * 16;

  f32x4 acc = (f32x4){0.f, 0.f, 0.f, 0.f};
  const ushort* ap = A + (size_t)(mbase + r) * DI + ko;
  const ushort* wp = W + (size_t)(nbase + r) * DI + ko;
#pragma unroll 4
  for (int k0 = 0; k0 < DI; k0 += 32) {
    const bf16x8 av = *(const bf16x8*)(ap + k0);
    const bf16x8 bv = *(const bf16x8*)(wp + k0);
    acc = __builtin_amdgcn_mfma_f32_16x16x32_bf16(av, bv, acc, 0, 0, 0);
  }
  const int cc = lane & 15, rr = (lane >> 4) * 4;
  if (nbase < 32) {
#pragma unroll
    for (int j = 0; j < 4; ++j)
      dt_lds[rr + j][nbase + cc] = f2bf(acc[j]);
  } else {
#pragma unroll
    for (int j = 0; j < 4; ++j)
      C[(size_t)(mbase + rr + j) * 64 + nbase + cc] = f2bf(acc[j]);
  }
  __syncthreads();

  const bf16x8 ad = *(const bf16x8*)&dt_lds[r][ko];
  const int cwbase = wv * 256;
#pragma unroll
  for (int ni = 0; ni < 16; ++ni) {
    const bf16x8 bvv = *(const bf16x8*)(dtw + (size_t)(cwbase + ni * 16 + r) * 32 + ko);
    f32x4 accd = (f32x4){0.f, 0.f, 0.f, 0.f};
    accd = __builtin_amdgcn_mfma_f32_16x16x32_bf16(ad, bvv, accd, 0, 0, 0);
    const int col = cwbase + ni * 16 + cc;
    const float bsv = dtb[col];
    ushort4 ov;
#pragma unroll
    for (int j = 0; j < 4; ++j) {
      float v = accd[j] + bsv;
      v = (v > 20.f) ? v : __logf(1.f + __expf(v));
      ((ushort*)&ov)[j] = f2bf(v);
    }
    *(ushort4*)(db + ((size_t)blockIdx.x * 1024 + col) * 16 + rr) = ov;
  }
}

// ---------------------------------------------------------------------------
// Depthwise conv (k=4) + bias + silu, chunk-per-thread version.
// ---------------------------------------------------------------------------
#define CONV_LOADW(pos, dst)                                                   \
  if ((pos) >= 0 && (pos) < Ln) {                                              \
    const ushort4 xv = *(const ushort4*)(xz + (size_t)(bLn + (pos)) * 2048 + c0); \
    dst[0] = bf2f(xv.x); dst[1] = bf2f(xv.y);                                  \
    dst[2] = bf2f(xv.z); dst[3] = bf2f(xv.w);                                  \
  } else { dst[0] = 0.f; dst[1] = 0.f; dst[2] = 0.f; dst[3] = 0.f; }

#define CONV_STEP(tpos, s)                                                     \
  {                                                                            \
    _Pragma("unroll")                                                          \
    for (int ch = 0; ch < 4; ++ch) {                                           \
      wa[ch] = wb[ch]; wb[ch] = wc[ch]; wc[ch] = wd[ch];                       \
    }                                                                          \
    {                                                                          \
      const ushort4 xv = *(const ushort4*)(xz + (size_t)(bLn + (tpos)) * 2048 + c0); \
      wd[0] = bf2f(xv.x); wd[1] = bf2f(xv.y);                                  \
      wd[2] = bf2f(xv.z); wd[3] = bf2f(xv.w);                                  \
    }                                                                          \
    const ushort4 zv = *(const ushort4*)(xz + (size_t)(bLn + (tpos)) * 2048 + DI + c0); \
    float zf[4];                                                               \
    zf[0] = bf2f(zv.x); zf[1] = bf2f(zv.y); zf[2] = bf2f(zv.z); zf[3] = bf2f(zv.w); \
    ushort4 ur;                                                                \
    _Pragma("unroll")                                                          \
    for (int ch = 0; ch < 4; ++ch) {                                           \
      float sa = bias[ch] + wgt[ch][0] * wa[ch] + wgt[ch][1] * wb[ch]          \
               + wgt[ch][2] * wc[ch] + wgt[ch][3] * wd[ch];                    \
      const ushort su = f2bf(sa / (1.f + __expf(-sa)));                        \
      ubuf[ch][(s) >> 3][(s) & 7] = su;                                        \
      ((ushort*)&ur)[ch] = su;                                                 \
      gbuf[ch][(s) >> 3][(s) & 7] = f2bf(zf[ch] / (1.f + __expf(-zf[ch])));    \
    }                                                                          \
    *(ushort4*)(uo + (size_t)(bLn + (tpos)) * 1024 + c0) = ur;                 \
  }

__global__ __launch_bounds__(256, 2)
void conv_k(const ushort* __restrict__ xz_f, const ushort* __restrict__ xz_r,
            const float* __restrict__ fw, const float* __restrict__ fb,
            const float* __restrict__ rw, const float* __restrict__ rb,
            ushort* __restrict__ u_f, ushort* __restrict__ u_r,
            ushort* __restrict__ ub_f, ushort* __restrict__ ub_r,
            ushort* __restrict__ gb_f, ushort* __restrict__ gb_r)
{
  const int idx = blockIdx.x * 256 + threadIdx.x;
  const int cg = idx & 255, chunk = (idx >> 8) & 31, b = (idx >> 13) & 7, dir = idx >> 16;
  const int c0 = cg * 4;
  const int bLn = b * Ln;

  const ushort* xz = dir ? xz_r : xz_f;
  const float* cw = dir ? rw : fw;
  const float* cb = dir ? rb : fb;
  ushort* uo = dir ? u_r : u_f;
  ushort* ub = dir ? ub_r : ub_f;
  ushort* gb = dir ? gb_r : gb_f;

  float bias[4];
  float wgt[4][4];
#pragma unroll
  for (int ch = 0; ch < 4; ++ch) {
    bias[ch] = cb[c0 + ch];
    const float4 w4 = *(const float4*)(cw + (size_t)(c0 + ch) * 4);
    wgt[ch][0] = w4.x; wgt[ch][1] = w4.y; wgt[ch][2] = w4.z; wgt[ch][3] = w4.w;
  }

  float wa[4], wb[4], wc[4], wd[4];
  ushort8v ubuf[4][2], gbuf[4][2];

  if (!dir) {
    const int t0 = chunk * 16;
    CONV_LOADW(t0 - 3, wb)
    CONV_LOADW(t0 - 2, wc)
    CONV_LOADW(t0 - 1, wd)
#pragma unroll
    for (int s = 0; s < 16; ++s) CONV_STEP(t0 + s, s)
  } else {
    const int t1 = chunk * 16 + 15;
    CONV_LOADW(t1 + 3, wb)
    CONV_LOADW(t1 + 2, wc)
    CONV_LOADW(t1 + 1, wd)
#pragma unroll
    for (int i = 0; i < 16; ++i) CONV_STEP(t1 - i, 15 - i)
  }

  const size_t blkBase = ((size_t)(b * 32 + chunk) * 1024 + c0) * 16;
#pragma unroll
  for (int ch = 0; ch < 4; ++ch) {
    *(ushort8v*)(ub + blkBase + (size_t)ch * 16)     = ubuf[ch][0];
    *(ushort8v*)(ub + blkBase + (size_t)ch * 16 + 8) = ubuf[ch][1];
    *(ushort8v*)(gb + blkBase + (size_t)ch * 16)     = gbuf[ch][0];
    *(ushort8v*)(gb + blkBase + (size_t)ch * 16 + 8) = gbuf[ch][1];
  }
}

// ---------------------------------------------------------------------------
// Chunked selective scan. hloc/hin in bf16 (ushort4/group).
// bid bits: part(2) | chunk(5) | b(3) | dir(1) -> 2048 blocks.
// ---------------------------------------------------------------------------
#define SCAN1_STEP(s, e)                                                       \
  {                                                                            \
    const float dl = bf2f((ushort)(((e) < 8) ? dv0[(e)] : dv1[(e) - 8]));      \
    const float uv = bf2f((ushort)(((e) < 8) ? uv0[(e)] : uv1[(e) - 8]));      \
    const float du = dl * uv;                                                  \
    S += dl;                                                                   \
    _Pragma("unroll")                                                          \
    for (int g = 0; g < 4; ++g) {                                              \
      const float4 Bv = ((const float4*)Bs[(s)])[g];                           \
      h[g*4+0] = fmaf(EXP2F(dl * a2[g*4+0]), h[g*4+0], du * Bv.x);             \
      h[g*4+1] = fmaf(EXP2F(dl * a2[g*4+1]), h[g*4+1], du * Bv.y);             \
      h[g*4+2] = fmaf(EXP2F(dl * a2[g*4+2]), h[g*4+2], du * Bv.z);             \
      h[g*4+3] = fmaf(EXP2F(dl * a2[g*4+3]), h[g*4+3], du * Bv.w);             \
    }                                                                          \
  }

__global__ __launch_bounds__(256, 4)
void scan1_k(const ushort* __restrict__ db_f, const ushort* __restrict__ db_r,
             const ushort* __restrict__ ub_f, const ushort* __restrict__ ub_r,
             const ushort* __restrict__ dbc_f, const ushort* __restrict__ dbc_r,
             const float* __restrict__ fA, const float* __restrict__ rA,
             ushort4* __restrict__ hloc, float* __restrict__ Sa)
{
  const int bid = blockIdx.x;
  const int part = bid & 3, chunk = (bid >> 2) & 31, b = (bid >> 7) & 7, dir = bid >> 10;
  const int tid = threadIdx.x, c = part * 256 + tid;
  const int bd = dir * 8 + b;

  const ushort* dblk = dir ? db_r : db_f;
  const ushort* ublk = dir ? ub_r : ub_f;
  const ushort* dbc  = dir ? dbc_r : dbc_f;
  const float*  Alog = dir ? rA : fA;

  __shared__ float Bs[CLS][16];      // 1 KB
  {
    const int s = tid >> 4, n = tid & 15;
    const int t = dir ? (Ln - 1 - (chunk * CLS + s)) : (chunk * CLS + s);
    Bs[s][n] = bf2f(dbc[(size_t)(b * Ln + t) * 64 + 32 + n]);
  }
  __syncthreads();

  float a2[16];
  {
    const float4* Ar = (const float4*)(Alog + (size_t)c * 16);
#pragma unroll
    for (int g = 0; g < 4; ++g) {
      float4 av = Ar[g];
      a2[g*4+0] = -__expf(av.x) * 1.44269504f;
      a2[g*4+1] = -__expf(av.y) * 1.44269504f;
      a2[g*4+2] = -__expf(av.z) * 1.44269504f;
      a2[g*4+3] = -__expf(av.w) * 1.44269504f;
    }
  }

  const int sc = dir ? (31 - chunk) : chunk;
  const size_t blkBase = (((size_t)(b * 32 + sc)) * 1024 + c) * 16;
  const ushort8v dv0 = *(const ushort8v*)(dblk + blkBase);
  const ushort8v dv1 = *(const ushort8v*)(dblk + blkBase + 8);
  const ushort8v uv0 = *(const ushort8v*)(ublk + blkBase);
  const ushort8v uv1 = *(const ushort8v*)(ublk + blkBase + 8);

  float h[16];
#pragma unroll
  for (int n = 0; n < 16; ++n) h[n] = 0.f;
  float S = 0.f;

  if (!dir) {
#pragma unroll
    for (int s = 0; s < CLS; ++s) SCAN1_STEP(s, s)
  } else {
#pragma unroll
    for (int s = 0; s < CLS; ++s) SCAN1_STEP(s, 15 - s)
  }

#pragma unroll
  for (int g = 0; g < 4; ++g) {
    const size_t o = ((size_t)g * 16 * NCH + (size_t)bd * NCH + chunk) * 1024 + c;
    ushort4 hv;
    hv.x = f2bf(h[g*4+0]); hv.y = f2bf(h[g*4+1]);
    hv.z = f2bf(h[g*4+2]); hv.w = f2bf(h[g*4+3]);
    hloc[o] = hv;
  }
  Sa[((size_t)bd * NCH + chunk) * 1024 + c] = S;
}

// Compose chunk-entry states in-place (hin overwrites hloc), fp32 carry.
__global__ __launch_bounds__(256, 4)
void scan2_k(ushort4* __restrict__ hloc, const float* __restrict__ Sa,
             const float* __restrict__ fA, const float* __restrict__ rA)
{
  const int idx = blockIdx.x * 256 + threadIdx.x;   // 65536
  const int ng = idx & 3, c = (idx >> 2) & 1023, b = (idx >> 12) & 7, dir = idx >> 15;
  const int bd = dir * 8 + b;
  const float* Alog = dir ? rA : fA;
  float a2[4];
  {
    const float4 av = *(const float4*)(Alog + (size_t)c * 16 + ng * 4);
    a2[0] = -__expf(av.x) * 1.44269504f;
    a2[1] = -__expf(av.y) * 1.44269504f;
    a2[2] = -__expf(av.z) * 1.44269504f;
    a2[3] = -__expf(av.w) * 1.44269504f;
  }
  float4 h = (float4){0.f, 0.f, 0.f, 0.f};
#pragma unroll
  for (int k = 0; k < NCH; ++k) {
    const size_t o = ((size_t)ng * 16 * NCH + (size_t)bd * NCH + k) * 1024 + c;
    const float S = Sa[((size_t)bd * NCH + k) * 1024 + c];
    const ushort4 hlb = hloc[o];
    const float hlx = bf2f(hlb.x), hly = bf2f(hlb.y);
    const float hlz = bf2f(hlb.z), hlw = bf2f(hlb.w);
    ushort4 hw;
    hw.x = f2bf(h.x); hw.y = f2bf(h.y); hw.z = f2bf(h.z); hw.w = f2bf(h.w);
    hloc[o] = hw;
    h.x = fmaf(EXP2F(a2[0] * S), h.x, hlx);
    h.y = fmaf(EXP2F(a2[1] * S), h.y, hly);
    h.z = fmaf(EXP2F(a2[2] * S), h.z, hlz);
    h.w = fmaf(EXP2F(a2[3] * S), h.w, hlw);
  }
}

#define SCAN3_STEP(s, e)                                                       \
  {                                                                            \
    const float dl = bf2f((ushort)(((e) < 8) ? dv0[(e)] : dv1[(e) - 8]));      \
    const float uv = bf2f((ushort)(((e) < 8) ? uv0[(e)] : uv1[(e) - 8]));      \
    const float gg = bf2f((ushort)(((e) < 8) ? gv0[(e)] : gv1[(e) - 8]));      \
    const float du = dl * uv;                                                  \
    float y = 0.f;                                                             \
    _Pragma("unroll")                                                          \
    for (int g = 0; g < 4; ++g) {                                              \
      const float4 Bv = ((const float4*)Bs[(s)])[g];                           \
      const float4 Cw = ((const float4*)Cs[(s)])[g];                           \
      h[g*4+0] = fmaf(EXP2F(dl * a2[g*4+0]), h[g*4+0], du * Bv.x);             \
      y = fmaf(h[g*4+0], Cw.x, y);                                             \
      h[g*4+1] = fmaf(EXP2F(dl * a2[g*4+1]), h[g*4+1], du * Bv.y);             \
      y = fmaf(h[g*4+1], Cw.y, y);                                             \
      h[g*4+2] = fmaf(EXP2F(dl * a2[g*4+2]), h[g*4+2], du * Bv.z);             \
      y = fmaf(h[g*4+2], Cw.z, y);                                             \
      h[g*4+3] = fmaf(EXP2F(dl * a2[g*4+3]), h[g*4+3], du * Bv.w);             \
      y = fmaf(h[g*4+3], Cw.w, y);                                             \
    }                                                                          \
    *ymp = f2bf((y + uv * Dc) * gg);                                           \
    ymp += stp;                                                                \
  }

__global__ __launch_bounds__(256, 4)
void scan3_k(const ushort* __restrict__ db_f, const ushort* __restrict__ db_r,
             const ushort* __restrict__ ub_f, const ushort* __restrict__ ub_r,
             const ushort* __restrict__ dbc_f, const ushort* __restrict__ dbc_r,
             const ushort* __restrict__ gb_f, const ushort* __restrict__ gb_r,
             const float* __restrict__ fA, const float* __restrict__ fD,
             const float* __restrict__ rA, const float* __restrict__ rD,
             const ushort4* __restrict__ hin,
             ushort* __restrict__ ym_f, ushort* __restrict__ ym_r)
{
  const int bid = blockIdx.x;
  const int part = bid & 3, chunk = (bid >> 2) & 31, b = (bid >> 7) & 7, dir = bid >> 10;
  const int tid = threadIdx.x, c = part * 256 + tid;
  const int bd = dir * 8 + b;

  const ushort* dblk = dir ? db_r : db_f;
  const ushort* ublk = dir ? ub_r : ub_f;
  const ushort* gblk = dir ? gb_r : gb_f;
  const ushort* dbc  = dir ? dbc_r : dbc_f;
  const float*  Alog = dir ? rA : fA;
  const float*  Dw   = dir ? rD : fD;
  ushort* ym         = dir ? ym_r : ym_f;

  __shared__ float Bs[CLS][16], Cs[CLS][16];   // 2 KB
  {
    const int s = tid >> 5, k = tid & 31;
#pragma unroll
    for (int p = 0; p < 2; ++p) {
      const int ss = s + p * 8;
      const int t = dir ? (Ln - 1 - (chunk * CLS + ss)) : (chunk * CLS + ss);
      const float val = bf2f(dbc[(size_t)(b * Ln + t) * 64 + 32 + k]);
      if (k < 16) Bs[ss][k] = val; else Cs[ss][k - 16] = val;
    }
  }
  __syncthreads();

  float a2[16];
  {
    const float4* Ar = (const float4*)(Alog + (size_t)c * 16);
#pragma unroll
    for (int g = 0; g < 4; ++g) {
      float4 av = Ar[g];
      a2[g*4+0] = -__expf(av.x) * 1.44269504f;
      a2[g*4+1] = -__expf(av.y) * 1.44269504f;
      a2[g*4+2] = -__expf(av.z) * 1.44269504f;
      a2[g*4+3] = -__expf(av.w) * 1.44269504f;
    }
  }
  const float Dc = Dw[c];

  const int sc = dir ? (31 - chunk) : chunk;
  const size_t blkBase = (((size_t)(b * 32 + sc)) * 1024 + c) * 16;
  const ushort8v dv0 = *(const ushort8v*)(dblk + blkBase);
  const ushort8v dv1 = *(const ushort8v*)(dblk + blkBase + 8);
  const ushort8v uv0 = *(const ushort8v*)(ublk + blkBase);
  const ushort8v uv1 = *(const ushort8v*)(ublk + blkBase + 8);
  const ushort8v gv0 = *(const ushort8v*)(gblk + blkBase);
  const ushort8v gv1 = *(const ushort8v*)(gblk + blkBase + 8);

  float h[16];
#pragma unroll
  for (int g = 0; g < 4; ++g) {
    const size_t o = ((size_t)g * 16 * NCH + (size_t)bd * NCH + chunk) * 1024 + c;
    const ushort4 hv = hin[o];
    h[g*4+0] = bf2f(hv.x); h[g*4+1] = bf2f(hv.y);
    h[g*4+2] = bf2f(hv.z); h[g*4+3] = bf2f(hv.w);
  }

  const int t0 = dir ? (Ln - 1 - chunk * CLS) : (chunk * CLS);
  const int stp = (dir ? -1 : 1) * DI;
  ushort* ymp = ym + (size_t)(b * Ln + t0) * DI + c;

  if (!dir) {
#pragma unroll
    for (int s = 0; s < CLS; ++s) SCAN3_STEP(s, s)
  } else {
#pragma unroll
    for (int s = 0; s < CLS; ++s) SCAN3_STEP(s, 15 - s)
  }
}

// ---------------------------------------------------------------------------
// LayerNorm over 512 cols of (a+b). One block per row.
// ---------------------------------------------------------------------------
template<int OUTF32>
__global__ __launch_bounds__(256)
void ln_k(const ushort* __restrict__ a, const ushort* __restrict__ b,
          const float* __restrict__ g, const float* __restrict__ bb,
          void* __restrict__ outv)
{
  const int row = blockIdx.x, tid = threadIdx.x;
  const size_t base = (size_t)row * DM;
  float v0 = bf2f(a[base + tid]) + bf2f(b[base + tid]);
  float v1 = bf2f(a[base + tid + 256]) + bf2f(b[base + tid + 256]);
  float s1 = v0 + v1, s2 = v0 * v0 + v1 * v1;
  for (int o = 32; o; o >>= 1) { s1 += __shfl_down(s1, o); s2 += __shfl_down(s2, o); }
  __shared__ float l1[4], l2[4];
  const int wv = tid >> 6, ln = tid & 63;
  if (ln == 0) { l1[wv] = s1; l2[wv] = s2; }
  __syncthreads();
  const float t1 = l1[0] + l1[1] + l1[2] + l1[3];
  const float t2 = l2[0] + l2[1] + l2[2] + l2[3];
  const float mean = t1 * (1.f / 512.f);
  const float var = t2 * (1.f / 512.f) - mean * mean;
  const float rs = rsqrtf(var + 1e-5f);
  const float o0 = (v0 - mean) * rs * g[tid] + bb[tid];
  const float o1 = (v1 - mean) * rs * g[tid + 256] + bb[tid + 256];
  if (OUTF32) {
    ((float*)outv)[base + tid] = o0;
    ((float*)outv)[base + tid + 256] = o1;
  } else {
    ((ushort*)outv)[base + tid] = f2bf(o0);
    ((ushort*)outv)[base + tid + 256] = f2bf(o1);
  }
}

// ---------------------------------------------------------------------------
extern "C" void kernel_launch(void* const* d_in, const int* in_sizes, int n_in,
                              void* d_out, int out_size, void* d_ws, size_t ws_size,
                              hipStream_t stream)
{
  const float* x        = (const float*)d_in[0];
  const float* f_in_w   = (const float*)d_in[1];
  const float* f_conv_w = (const float*)d_in[2];
  const float* f_conv_b = (const float*)d_in[3];
  const float* f_xproj  = (const float*)d_in[4];
  const float* f_dt_w   = (const float*)d_in[5];
  const float* f_dt_b   = (const float*)d_in[6];
  const float* f_A_log  = (const float*)d_in[7];
  const float* f_D      = (const float*)d_in[8];
  const float* f_out_w  = (const float*)d_in[9];
  const float* r_in_w   = (const float*)d_in[10];
  const float* r_conv_w = (const float*)d_in[11];
  const float* r_conv_b = (const float*)d_in[12];
  const float* r_xproj  = (const float*)d_in[13];
  const float* r_dt_w   = (const float*)d_in[14];
  const float* r_dt_b   = (const float*)d_in[15];
  const float* r_A_log  = (const float*)d_in[16];
  const float* r_D      = (const float*)d_in[17];
  const float* r_out_w  = (const float*)d_in[18];
  const float* conv1_w  = (const float*)d_in[19];
  const float* conv1_b  = (const float*)d_in[20];
  const float* conv2_w  = (const float*)d_in[21];
  const float* conv2_b  = (const float*)d_in[22];
  const float* ln1_g    = (const float*)d_in[23];
  const float* ln1_b    = (const float*)d_in[24];
  const float* ln2_g    = (const float*)d_in[25];
  const float* ln2_b    = (const float*)d_in[26];

  char* ws = (char*)d_ws;
  size_t off = 0;
  auto alloc = [&](size_t bytes) -> void* {
    void* p = ws + off;
    off += (bytes + 255) & ~(size_t)255;
    return p;
  };
  ushort* x_b     = (ushort*)alloc((size_t)Mtok * DM * 2);
  ushort* f_inw_b = (ushort*)alloc((size_t)2 * DI * DM * 2);
  ushort* r_inw_b = (ushort*)alloc((size_t)2 * DI * DM * 2);
  ushort* f_xp_b  = (ushort*)alloc((size_t)64 * DI * 2);
  ushort* r_xp_b  = (ushort*)alloc((size_t)64 * DI * 2);
  ushort* f_dtw_b = (ushort*)alloc((size_t)DI * 32 * 2);
  ushort* r_dtw_b = (ushort*)alloc((size_t)DI * 32 * 2);
  ushort* f_ow_b  = (ushort*)alloc((size_t)DM * DI * 2);
  ushort* r_ow_b  = (ushort*)alloc((size_t)DM * DI * 2);
  ushort* c1w_b   = (ushort*)alloc((size_t)DFF * DM * 2);
  ushort* c2w_b   = (ushort*)alloc((size_t)DM * DFF * 2);
  ushort* xz_f    = (ushort*)alloc((size_t)Mtok * 2048 * 2);
  ushort* xz_r    = (ushort*)alloc((size_t)Mtok * 2048 * 2);
  ushort* u_f     = (ushort*)alloc((size_t)Mtok * DI * 2);
  ushort* u_r     = (ushort*)alloc((size_t)Mtok * DI * 2);
  ushort* ub_f    = (ushort*)alloc((size_t)Mtok * DI * 2);
  ushort* ub_r    = (ushort*)alloc((size_t)Mtok * DI * 2);
  ushort* gb_f    = (ushort*)alloc((size_t)Mtok * DI * 2);
  ushort* gb_r    = (ushort*)alloc((size_t)Mtok * DI * 2);
  ushort* dbc_f   = (ushort*)alloc((size_t)Mtok * 64 * 2);
  ushort* dbc_r   = (ushort*)alloc((size_t)Mtok * 64 * 2);
  ushort* db_f    = (ushort*)alloc((size_t)Mtok * DI * 2);
  ushort* db_r    = (ushort*)alloc((size_t)Mtok * DI * 2);
  ushort* ym_f    = (ushort*)alloc((size_t)Mtok * DI * 2);
  ushort* ym_r    = (ushort*)alloc((size_t)Mtok * DI * 2);
  ushort* mo      = (ushort*)alloc((size_t)Mtok * DM * 2);
  ushort* x1      = (ushort*)alloc((size_t)Mtok * DM * 2);
  ushort* h1b     = (ushort*)alloc((size_t)Mtok * DFF * 2);
  ushort* y2      = (ushort*)alloc((size_t)Mtok * DM * 2);
  ushort4* hloc   = (ushort4*)alloc((size_t)4 * 16 * NCH * 1024 * 8);
  float*  Sa      = (float*)alloc((size_t)16 * NCH * 1024 * 4);
  (void)ws_size; (void)in_sizes; (void)n_in; (void)out_size;

  // 0. fp32 -> bf16 conversion (one launch)
  {
    CvtTab tb;
    int blk = 0, ji = 0;
    auto add = [&](const float* s, ushort* d, int n) {
      tb.j[ji].src = s; tb.j[ji].dst = d; tb.j[ji].blk0 = blk; tb.j[ji]._pad = 0;
      blk += n / 2048; ++ji;
    };
    add(x,       x_b,     Mtok * DM);
    add(f_in_w,  f_inw_b, 2 * DI * DM);
    add(r_in_w,  r_inw_b, 2 * DI * DM);
    add(f_xproj, f_xp_b,  64 * DI);
    add(r_xproj, r_xp_b,  64 * DI);
    add(f_dt_w,  f_dtw_b, DI * 32);
    add(r_dt_w,  r_dtw_b, DI * 32);
    add(f_out_w, f_ow_b,  DM * DI);
    add(r_out_w, r_ow_b,  DM * DI);
    add(conv1_w, c1w_b,   DFF * DM);
    add(conv2_w, c2w_b,   DM * DFF);
    cvt_k<<<dim3(blk), 256, 0, stream>>>(tb, ji);
  }

  // 1. xz = x @ in_w.T (f/r z-batched), LDS GEMM 128x128 (+XCD swizzle)
  gemm_lds<128, 128, 2, 2, 0, 0, 0><<<dim3(32, 16, 2), 256, 0, stream>>>(
      x_b, f_inw_b, xz_f, nullptr, x_b, r_inw_b, xz_r, nullptr,
      nullptr, nullptr, DM, DM, DM, 2048, 0, 0, 0);

  // 2. depthwise conv + silu: u row-major + blocked u/gz (coalesced stores)
  conv_k<<<dim3(512), 256, 0, stream>>>(
      xz_f, xz_r, f_conv_w, f_conv_b, r_conv_w, r_conv_b,
      u_f, u_r, ub_f, ub_r, gb_f, gb_r);

  // 3. fused xproj + dt: dbc B/C cols + blocked delta
  xproj_k<<<dim3(256, 1, 2), 256, 0, stream>>>(
      u_f, f_xp_b, dbc_f, u_r, r_xp_b, dbc_r,
      f_dtw_b, f_dt_b, r_dtw_b, r_dt_b, db_f, db_r);

  // 4. chunked scan: local -> compose (in-place hin) -> emit
  scan1_k<<<dim3(2048), 256, 0, stream>>>(
      db_f, db_r, ub_f, ub_r, dbc_f, dbc_r, f_A_log, r_A_log, hloc, Sa);
  scan2_k<<<dim3(256), 256, 0, stream>>>(hloc, Sa, f_A_log, r_A_log);
  scan3_k<<<dim3(2048), 256, 0, stream>>>(
      db_f, db_r, ub_f, ub_r, dbc_f, dbc_r, gb_f, gb_r,
      f_A_log, f_D, r_A_log, r_D, hloc, ym_f, ym_r);

  // 5. mo = ym_f @ f_out_w.T + ym_r @ r_out_w.T, LDS GEMM 64x64 dual-K
  gemm_lds<64, 64, 2, 2, 0, 0, 1><<<dim3(64, 8, 1), 256, 0, stream>>>(
      ym_f, f_ow_b, mo, nullptr, nullptr, nullptr, nullptr, nullptr,
      ym_r, r_ow_b, DI, DI, DI, DM, DI, DI, DI);

  // 6. x1 = LN(x + mo)
  ln_k<0><<<dim3(Mtok), 256, 0, stream>>>(x_b, mo, ln1_g, ln1_b, x1);

  // 7. h1 = fast_gelu(x1 @ conv1_w.T + b1), LDS GEMM 128x128
  gemm_lds<128, 128, 2, 2, 3, 0, 0><<<dim3(32, 16, 1), 256, 0, stream>>>(
      x1, c1w_b, h1b, conv1_b, nullptr, nullptr, nullptr, nullptr,
      nullptr, nullptr, DM, DM, DM, DFF, 0, 0, 0);

  // 8. y2 = h1 @ conv2_w.T + b2, LDS GEMM 64x64
  gemm_lds<64, 64, 2, 2, 1, 0, 0><<<dim3(64, 8, 1), 256, 0, stream>>>(
      h1b, c2w_b, y2, conv2_b, nullptr, nullptr, nullptr, nullptr,
      nullptr, nullptr, DFF, DFF, DFF, DM, 0, 0, 0);

  // 9. out = LN(x1 + y2) -> fp32
  ln_k<1><<<dim3(Mtok), 256, 0, stream>>>(x1, y2, ln2_g, ln2_b, (float*)d_out);
}

// Round 19
// 234.372 us; speedup vs baseline: 1.0285x; 1.0285x over previous
//
#include <hip/hip_runtime.h>
#include <hip/hip_bf16.h>

#define DEVINL __device__ __forceinline__

typedef short bf16x8 __attribute__((ext_vector_type(8)));
typedef float f32x4 __attribute__((ext_vector_type(4)));
typedef ushort ushort8v __attribute__((ext_vector_type(8)));

static constexpr int Bn = 8, Ln = 512, DM = 512, DI = 1024, DS = 16, DFF = 2048;
static constexpr int Mtok = Bn * Ln; // 4096
static constexpr int NCH = 32, CLS = 16; // scan chunks, chunk length

DEVINL float bf2f(ushort u) { union { uint i; float f; } v; v.i = uint(u) << 16; return v.f; }
DEVINL ushort f2bf(float f) {
  union { float f; uint i; } v; v.f = f;
  uint r = v.i + 0x7FFF + ((v.i >> 16) & 1);
  return ushort(r >> 16);
}

// Fast hardware exp2 (single v_exp_f32).
#if __has_builtin(__builtin_amdgcn_exp2f)
#define EXP2F(x) __builtin_amdgcn_exp2f(x)
#else
#define EXP2F(x) __expf((x) * 0.69314718056f)
#endif

// async global->LDS, 16B per lane.
#define GLOAD16(gp, lp)                                                        \
  __builtin_amdgcn_global_load_lds(                                            \
      (const __attribute__((address_space(1))) void*)(gp),                     \
      (__attribute__((address_space(3))) void*)(lp), 16, 0, 0)

// ---------------------------------------------------------------------------
// fp32 -> bf16 bulk converter.
// ---------------------------------------------------------------------------
struct CvtJob { const float* src; ushort* dst; int blk0; int _pad; };
struct CvtTab { CvtJob j[11]; };

__global__ __launch_bounds__(256)
void cvt_k(CvtTab tb, int njobs) {
  const int blk = blockIdx.x;
  int ji = 0;
#pragma unroll
  for (int k = 1; k < 11; ++k)
    if (k < njobs && tb.j[k].blk0 <= blk) ji = k;
  const CvtJob J = tb.j[ji];
  const size_t base = (size_t)(blk - J.blk0) * 2048 + (size_t)threadIdx.x * 8;
  float4 a = *(const float4*)(J.src + base);
  float4 b = *(const float4*)(J.src + base + 4);
  ushort8v o;
  o[0] = f2bf(a.x); o[1] = f2bf(a.y); o[2] = f2bf(a.z); o[3] = f2bf(a.w);
  o[4] = f2bf(b.x); o[5] = f2bf(b.y); o[6] = f2bf(b.z); o[7] = f2bf(b.w);
  *(ushort8v*)(J.dst + base) = o;
}

// ---------------------------------------------------------------------------
// m97-structure LDS GEMM: C(M,N) = A(M,K) @ W(N,K)^T, bf16, BK=32, 4 waves.
// EPI: 0 none, 1 bias, 3 bias+fast-gelu.
// ---------------------------------------------------------------------------
template<int BM, int BN, int WM, int WN, int EPI, int OUTF32, int DUALK>
__global__ __launch_bounds__(256)
void gemm_lds(const ushort* __restrict__ A0, const ushort* __restrict__ W0,
              void* __restrict__ C0v, const float* __restrict__ bias0,
              const ushort* __restrict__ A1, const ushort* __restrict__ W1,
              void* __restrict__ C1v, const float* __restrict__ bias1,
              const ushort* __restrict__ Ab0, const ushort* __restrict__ Wb0,
              int K, int lda, int ldw, int ldc, int Kb, int ldab, int ldwb)
{
  constexpr int MT = BM / WM / 16, NT = BN / WN / 16;
  constexpr int RA = BM * 32 / 2048, RB = BN * 32 / 2048;
  __shared__ ushort As[BM * 32];
  __shared__ ushort Bs[BN * 32];

  const ushort* Ap = blockIdx.z ? A1 : A0;
  const ushort* Wp = blockIdx.z ? W1 : W0;
  void* Cv         = blockIdx.z ? C1v : C0v;
  const float* bia = blockIdx.z ? bias1 : bias0;

  const int tid = threadIdx.x, lane = tid & 63, wv = tid >> 6;
  const int wm = wv / WN, wn = wv % WN;
  const int mbase = blockIdx.x * BM, nbase = blockIdx.y * BN;
  const int r = lane & 15, ko = (lane >> 4) * 8;

  f32x4 acc[MT][NT];
#pragma unroll
  for (int mi = 0; mi < MT; ++mi)
#pragma unroll
    for (int ni = 0; ni < NT; ++ni) acc[mi][ni] = (f32x4){0.f, 0.f, 0.f, 0.f};

  for (int blkK = 0; blkK < (DUALK ? 2 : 1); ++blkK) {
    const ushort* Au = (DUALK && blkK) ? Ab0 : Ap;
    const ushort* Wu = (DUALK && blkK) ? Wb0 : Wp;
    const int Ku  = (DUALK && blkK) ? Kb : K;
    const int ldau = (DUALK && blkK) ? ldab : lda;
    const int ldwu = (DUALK && blkK) ? ldwb : ldw;

    for (int k0 = 0; k0 < Ku; k0 += 32) {
      __syncthreads();
#pragma unroll
      for (int i = 0; i < RA; ++i) {
        const int e = i * 2048 + wv * 512 + lane * 8;
        const int row = e >> 5, ck = e & 31;
        GLOAD16(Au + (size_t)(mbase + row) * ldau + k0 + ck,
                (ushort*)As + i * 2048 + wv * 512);
      }
#pragma unroll
      for (int i = 0; i < RB; ++i) {
        const int e = i * 2048 + wv * 512 + lane * 8;
        const int row = e >> 5, ck = e & 31;
        GLOAD16(Wu + (size_t)(nbase + row) * ldwu + k0 + ck,
                (ushort*)Bs + i * 2048 + wv * 512);
      }
      __syncthreads();

      bf16x8 af[MT], bfv[NT];
#pragma unroll
      for (int mi = 0; mi < MT; ++mi)
        af[mi] = *(const bf16x8*)&As[(wm * MT * 16 + mi * 16 + r) * 32 + ko];
#pragma unroll
      for (int ni = 0; ni < NT; ++ni)
        bfv[ni] = *(const bf16x8*)&Bs[(wn * NT * 16 + ni * 16 + r) * 32 + ko];
#pragma unroll
      for (int mi = 0; mi < MT; ++mi)
#pragma unroll
        for (int ni = 0; ni < NT; ++ni)
          acc[mi][ni] = __builtin_amdgcn_mfma_f32_16x16x32_bf16(af[mi], bfv[ni], acc[mi][ni], 0, 0, 0);
    }
  }

  const int rr = (lane >> 4) * 4, cc = lane & 15;
#pragma unroll
  for (int ni = 0; ni < NT; ++ni) {
    const int col = nbase + wn * NT * 16 + ni * 16 + cc;
    float bsv = 0.f;
    if (EPI >= 1) bsv = bia[col];
#pragma unroll
    for (int mi = 0; mi < MT; ++mi) {
#pragma unroll
      for (int j = 0; j < 4; ++j) {
        const int row = mbase + wm * MT * 16 + mi * 16 + rr + j;
        float v = acc[mi][ni][j] + bsv;
        if (EPI == 3) {
          const float t = v * (0.7978845608f + v * v * 0.0356774081f);
          v = v / (1.f + EXP2F(t * -2.885390082f));
        }
        if (OUTF32) ((float*)Cv)[(size_t)row * ldc + col] = v;
        else        ((ushort*)Cv)[(size_t)row * ldc + col] = f2bf(v);
      }
    }
  }
}

// ---------------------------------------------------------------------------
// Fused xproj + dt projection.
// ---------------------------------------------------------------------------
__global__ __launch_bounds__(256)
void xproj_k(const ushort* __restrict__ A0, const ushort* __restrict__ W0,
             ushort* __restrict__ C0,
             const ushort* __restrict__ A1, const ushort* __restrict__ W1,
             ushort* __restrict__ C1,
             const ushort* __restrict__ dtw0, const float* __restrict__ dtb0,
             const ushort* __restrict__ dtw1, const float* __restrict__ dtb1,
             ushort* __restrict__ db0, ushort* __restrict__ db1)
{
  const ushort* A   = blockIdx.z ? A1 : A0;
  const ushort* W   = blockIdx.z ? W1 : W0;
  ushort* C         = blockIdx.z ? C1 : C0;
  const ushort* dtw = blockIdx.z ? dtw1 : dtw0;
  const float*  dtb = blockIdx.z ? dtb1 : dtb0;
  ushort* db        = blockIdx.z ? db1 : db0;

  __shared__ ushort dt_lds[16][32];

  const int tid = threadIdx.x, lane = tid & 63, wv = tid >> 6;
  const int r = lane & 15, ko = (lane >> 4) * 8;
  const int mbase = blockIdx.x * 16;
  const int nbase = wv * 16;

  f32x4 acc = (f32x4){0.f, 0.f, 0.f, 0.f};
  const ushort* ap = A + (size_t)(mbase + r) * DI + ko;
  const ushort* wp = W + (size_t)(nbase + r) * DI + ko;
#pragma unroll 4
  for (int k0 = 0; k0 < DI; k0 += 32) {
    const bf16x8 av = *(const bf16x8*)(ap + k0);
    const bf16x8 bv = *(const bf16x8*)(wp + k0);
    acc = __builtin_amdgcn_mfma_f32_16x16x32_bf16(av, bv, acc, 0, 0, 0);
  }
  const int cc = lane & 15, rr = (lane >> 4) * 4;
  if (nbase < 32) {
#pragma unroll
    for (int j = 0; j < 4; ++j)
      dt_lds[rr + j][nbase + cc] = f2bf(acc[j]);
  } else {
#pragma unroll
    for (int j = 0; j < 4; ++j)
      C[(size_t)(mbase + rr + j) * 64 + nbase + cc] = f2bf(acc[j]);
  }
  __syncthreads();

  const bf16x8 ad = *(const bf16x8*)&dt_lds[r][ko];
  const int cwbase = wv * 256;
#pragma unroll
  for (int ni = 0; ni < 16; ++ni) {
    const bf16x8 bvv = *(const bf16x8*)(dtw + (size_t)(cwbase + ni * 16 + r) * 32 + ko);
    f32x4 accd = (f32x4){0.f, 0.f, 0.f, 0.f};
    accd = __builtin_amdgcn_mfma_f32_16x16x32_bf16(ad, bvv, accd, 0, 0, 0);
    const int col = cwbase + ni * 16 + cc;
    const float bsv = dtb[col];
    ushort4 ov;
#pragma unroll
    for (int j = 0; j < 4; ++j) {
      float v = accd[j] + bsv;
      v = (v > 20.f) ? v : __logf(1.f + __expf(v));
      ((ushort*)&ov)[j] = f2bf(v);
    }
    *(ushort4*)(db + ((size_t)blockIdx.x * 1024 + col) * 16 + rr) = ov;
  }
}

// ---------------------------------------------------------------------------
// Depthwise conv (k=4) + bias + silu, chunk-per-thread version.
// ---------------------------------------------------------------------------
#define CONV_LOADW(pos, dst)                                                   \
  if ((pos) >= 0 && (pos) < Ln) {                                              \
    const ushort4 xv = *(const ushort4*)(xz + (size_t)(bLn + (pos)) * 2048 + c0); \
    dst[0] = bf2f(xv.x); dst[1] = bf2f(xv.y);                                  \
    dst[2] = bf2f(xv.z); dst[3] = bf2f(xv.w);                                  \
  } else { dst[0] = 0.f; dst[1] = 0.f; dst[2] = 0.f; dst[3] = 0.f; }

#define CONV_STEP(tpos, s)                                                     \
  {                                                                            \
    _Pragma("unroll")                                                          \
    for (int ch = 0; ch < 4; ++ch) {                                           \
      wa[ch] = wb[ch]; wb[ch] = wc[ch]; wc[ch] = wd[ch];                       \
    }                                                                          \
    {                                                                          \
      const ushort4 xv = *(const ushort4*)(xz + (size_t)(bLn + (tpos)) * 2048 + c0); \
      wd[0] = bf2f(xv.x); wd[1] = bf2f(xv.y);                                  \
      wd[2] = bf2f(xv.z); wd[3] = bf2f(xv.w);                                  \
    }                                                                          \
    const ushort4 zv = *(const ushort4*)(xz + (size_t)(bLn + (tpos)) * 2048 + DI + c0); \
    float zf[4];                                                               \
    zf[0] = bf2f(zv.x); zf[1] = bf2f(zv.y); zf[2] = bf2f(zv.z); zf[3] = bf2f(zv.w); \
    ushort4 ur;                                                                \
    _Pragma("unroll")                                                          \
    for (int ch = 0; ch < 4; ++ch) {                                           \
      float sa = bias[ch] + wgt[ch][0] * wa[ch] + wgt[ch][1] * wb[ch]          \
               + wgt[ch][2] * wc[ch] + wgt[ch][3] * wd[ch];                    \
      const ushort su = f2bf(sa / (1.f + __expf(-sa)));                        \
      ubuf[ch][(s) >> 3][(s) & 7] = su;                                        \
      ((ushort*)&ur)[ch] = su;                                                 \
      gbuf[ch][(s) >> 3][(s) & 7] = f2bf(zf[ch] / (1.f + __expf(-zf[ch])));    \
    }                                                                          \
    *(ushort4*)(uo + (size_t)(bLn + (tpos)) * 1024 + c0) = ur;                 \
  }

__global__ __launch_bounds__(256, 2)
void conv_k(const ushort* __restrict__ xz_f, const ushort* __restrict__ xz_r,
            const float* __restrict__ fw, const float* __restrict__ fb,
            const float* __restrict__ rw, const float* __restrict__ rb,
            ushort* __restrict__ u_f, ushort* __restrict__ u_r,
            ushort* __restrict__ ub_f, ushort* __restrict__ ub_r,
            ushort* __restrict__ gb_f, ushort* __restrict__ gb_r)
{
  const int idx = blockIdx.x * 256 + threadIdx.x;
  const int cg = idx & 255, chunk = (idx >> 8) & 31, b = (idx >> 13) & 7, dir = idx >> 16;
  const int c0 = cg * 4;
  const int bLn = b * Ln;

  const ushort* xz = dir ? xz_r : xz_f;
  const float* cw = dir ? rw : fw;
  const float* cb = dir ? rb : fb;
  ushort* uo = dir ? u_r : u_f;
  ushort* ub = dir ? ub_r : ub_f;
  ushort* gb = dir ? gb_r : gb_f;

  float bias[4];
  float wgt[4][4];
#pragma unroll
  for (int ch = 0; ch < 4; ++ch) {
    bias[ch] = cb[c0 + ch];
    const float4 w4 = *(const float4*)(cw + (size_t)(c0 + ch) * 4);
    wgt[ch][0] = w4.x; wgt[ch][1] = w4.y; wgt[ch][2] = w4.z; wgt[ch][3] = w4.w;
  }

  float wa[4], wb[4], wc[4], wd[4];
  ushort8v ubuf[4][2], gbuf[4][2];

  if (!dir) {
    const int t0 = chunk * 16;
    CONV_LOADW(t0 - 3, wb)
    CONV_LOADW(t0 - 2, wc)
    CONV_LOADW(t0 - 1, wd)
#pragma unroll
    for (int s = 0; s < 16; ++s) CONV_STEP(t0 + s, s)
  } else {
    const int t1 = chunk * 16 + 15;
    CONV_LOADW(t1 + 3, wb)
    CONV_LOADW(t1 + 2, wc)
    CONV_LOADW(t1 + 1, wd)
#pragma unroll
    for (int i = 0; i < 16; ++i) CONV_STEP(t1 - i, 15 - i)
  }

  const size_t blkBase = ((size_t)(b * 32 + chunk) * 1024 + c0) * 16;
#pragma unroll
  for (int ch = 0; ch < 4; ++ch) {
    *(ushort8v*)(ub + blkBase + (size_t)ch * 16)     = ubuf[ch][0];
    *(ushort8v*)(ub + blkBase + (size_t)ch * 16 + 8) = ubuf[ch][1];
    *(ushort8v*)(gb + blkBase + (size_t)ch * 16)     = gbuf[ch][0];
    *(ushort8v*)(gb + blkBase + (size_t)ch * 16 + 8) = gbuf[ch][1];
  }
}

// ---------------------------------------------------------------------------
// Chunked selective scan. hloc/hin in bf16 (ushort4/group).
// bid bits: part(2) | chunk(5) | b(3) | dir(1) -> 2048 blocks.
// ---------------------------------------------------------------------------
#define SCAN1_STEP(s, e)                                                       \
  {                                                                            \
    const float dl = bf2f((ushort)(((e) < 8) ? dv0[(e)] : dv1[(e) - 8]));      \
    const float uv = bf2f((ushort)(((e) < 8) ? uv0[(e)] : uv1[(e) - 8]));      \
    const float du = dl * uv;                                                  \
    S += dl;                                                                   \
    _Pragma("unroll")                                                          \
    for (int g = 0; g < 4; ++g) {                                              \
      const float4 Bv = ((const float4*)Bs[(s)])[g];                           \
      h[g*4+0] = fmaf(EXP2F(dl * a2[g*4+0]), h[g*4+0], du * Bv.x);             \
      h[g*4+1] = fmaf(EXP2F(dl * a2[g*4+1]), h[g*4+1], du * Bv.y);             \
      h[g*4+2] = fmaf(EXP2F(dl * a2[g*4+2]), h[g*4+2], du * Bv.z);             \
      h[g*4+3] = fmaf(EXP2F(dl * a2[g*4+3]), h[g*4+3], du * Bv.w);             \
    }                                                                          \
  }

__global__ __launch_bounds__(256, 4)
void scan1_k(const ushort* __restrict__ db_f, const ushort* __restrict__ db_r,
             const ushort* __restrict__ ub_f, const ushort* __restrict__ ub_r,
             const ushort* __restrict__ dbc_f, const ushort* __restrict__ dbc_r,
             const float* __restrict__ fA, const float* __restrict__ rA,
             ushort4* __restrict__ hloc, float* __restrict__ Sa)
{
  const int bid = blockIdx.x;
  const int part = bid & 3, chunk = (bid >> 2) & 31, b = (bid >> 7) & 7, dir = bid >> 10;
  const int tid = threadIdx.x, c = part * 256 + tid;
  const int bd = dir * 8 + b;

  const ushort* dblk = dir ? db_r : db_f;
  const ushort* ublk = dir ? ub_r : ub_f;
  const ushort* dbc  = dir ? dbc_r : dbc_f;
  const float*  Alog = dir ? rA : fA;

  __shared__ float Bs[CLS][16];      // 1 KB
  {
    const int s = tid >> 4, n = tid & 15;
    const int t = dir ? (Ln - 1 - (chunk * CLS + s)) : (chunk * CLS + s);
    Bs[s][n] = bf2f(dbc[(size_t)(b * Ln + t) * 64 + 32 + n]);
  }
  __syncthreads();

  float a2[16];
  {
    const float4* Ar = (const float4*)(Alog + (size_t)c * 16);
#pragma unroll
    for (int g = 0; g < 4; ++g) {
      float4 av = Ar[g];
      a2[g*4+0] = -__expf(av.x) * 1.44269504f;
      a2[g*4+1] = -__expf(av.y) * 1.44269504f;
      a2[g*4+2] = -__expf(av.z) * 1.44269504f;
      a2[g*4+3] = -__expf(av.w) * 1.44269504f;
    }
  }

  const int sc = dir ? (31 - chunk) : chunk;
  const size_t blkBase = (((size_t)(b * 32 + sc)) * 1024 + c) * 16;
  const ushort8v dv0 = *(const ushort8v*)(dblk + blkBase);
  const ushort8v dv1 = *(const ushort8v*)(dblk + blkBase + 8);
  const ushort8v uv0 = *(const ushort8v*)(ublk + blkBase);
  const ushort8v uv1 = *(const ushort8v*)(ublk + blkBase + 8);

  float h[16];
#pragma unroll
  for (int n = 0; n < 16; ++n) h[n] = 0.f;
  float S = 0.f;

  if (!dir) {
#pragma unroll
    for (int s = 0; s < CLS; ++s) SCAN1_STEP(s, s)
  } else {
#pragma unroll
    for (int s = 0; s < CLS; ++s) SCAN1_STEP(s, 15 - s)
  }

#pragma unroll
  for (int g = 0; g < 4; ++g) {
    const size_t o = ((size_t)g * 16 * NCH + (size_t)bd * NCH + chunk) * 1024 + c;
    ushort4 hv;
    hv.x = f2bf(h[g*4+0]); hv.y = f2bf(h[g*4+1]);
    hv.z = f2bf(h[g*4+2]); hv.w = f2bf(h[g*4+3]);
    hloc[o] = hv;
  }
  Sa[((size_t)bd * NCH + chunk) * 1024 + c] = S;
}

// Compose chunk-entry states in-place (hin overwrites hloc), fp32 carry.
__global__ __launch_bounds__(256, 4)
void scan2_k(ushort4* __restrict__ hloc, const float* __restrict__ Sa,
             const float* __restrict__ fA, const float* __restrict__ rA)
{
  const int idx = blockIdx.x * 256 + threadIdx.x;   // 65536
  const int ng = idx & 3, c = (idx >> 2) & 1023, b = (idx >> 12) & 7, dir = idx >> 15;
  const int bd = dir * 8 + b;
  const float* Alog = dir ? rA : fA;
  float a2[4];
  {
    const float4 av = *(const float4*)(Alog + (size_t)c * 16 + ng * 4);
    a2[0] = -__expf(av.x) * 1.44269504f;
    a2[1] = -__expf(av.y) * 1.44269504f;
    a2[2] = -__expf(av.z) * 1.44269504f;
    a2[3] = -__expf(av.w) * 1.44269504f;
  }
  float4 h = (float4){0.f, 0.f, 0.f, 0.f};
#pragma unroll
  for (int k = 0; k < NCH; ++k) {
    const size_t o = ((size_t)ng * 16 * NCH + (size_t)bd * NCH + k) * 1024 + c;
    const float S = Sa[((size_t)bd * NCH + k) * 1024 + c];
    const ushort4 hlb = hloc[o];
    const float hlx = bf2f(hlb.x), hly = bf2f(hlb.y);
    const float hlz = bf2f(hlb.z), hlw = bf2f(hlb.w);
    ushort4 hw;
    hw.x = f2bf(h.x); hw.y = f2bf(h.y); hw.z = f2bf(h.z); hw.w = f2bf(h.w);
    hloc[o] = hw;
    h.x = fmaf(EXP2F(a2[0] * S), h.x, hlx);
    h.y = fmaf(EXP2F(a2[1] * S), h.y, hly);
    h.z = fmaf(EXP2F(a2[2] * S), h.z, hlz);
    h.w = fmaf(EXP2F(a2[3] * S), h.w, hlw);
  }
}

#define SCAN3_STEP(s, e)                                                       \
  {                                                                            \
    const float dl = bf2f((ushort)(((e) < 8) ? dv0[(e)] : dv1[(e) - 8]));      \
    const float uv = bf2f((ushort)(((e) < 8) ? uv0[(e)] : uv1[(e) - 8]));      \
    const float gg = bf2f((ushort)(((e) < 8) ? gv0[(e)] : gv1[(e) - 8]));      \
    const float du = dl * uv;                                                  \
    float y = 0.f;                                                             \
    _Pragma("unroll")                                                          \
    for (int g = 0; g < 4; ++g) {                                              \
      const float4 Bv = ((const float4*)Bs[(s)])[g];                           \
      const float4 Cw = ((const float4*)Cs[(s)])[g];                           \
      h[g*4+0] = fmaf(EXP2F(dl * a2[g*4+0]), h[g*4+0], du * Bv.x);             \
      y = fmaf(h[g*4+0], Cw.x, y);                                             \
      h[g*4+1] = fmaf(EXP2F(dl * a2[g*4+1]), h[g*4+1], du * Bv.y);             \
      y = fmaf(h[g*4+1], Cw.y, y);                                             \
      h[g*4+2] = fmaf(EXP2F(dl * a2[g*4+2]), h[g*4+2], du * Bv.z);             \
      y = fmaf(h[g*4+2], Cw.z, y);                                             \
      h[g*4+3] = fmaf(EXP2F(dl * a2[g*4+3]), h[g*4+3], du * Bv.w);             \
      y = fmaf(h[g*4+3], Cw.w, y);                                             \
    }                                                                          \
    *ymp = f2bf((y + uv * Dc) * gg);                                           \
    ymp += stp;                                                                \
  }

__global__ __launch_bounds__(256, 4)
void scan3_k(const ushort* __restrict__ db_f, const ushort* __restrict__ db_r,
             const ushort* __restrict__ ub_f, const ushort* __restrict__ ub_r,
             const ushort* __restrict__ dbc_f, const ushort* __restrict__ dbc_r,
             const ushort* __restrict__ gb_f, const ushort* __restrict__ gb_r,
             const float* __restrict__ fA, const float* __restrict__ fD,
             const float* __restrict__ rA, const float* __restrict__ rD,
             const ushort4* __restrict__ hin,
             ushort* __restrict__ ym_f, ushort* __restrict__ ym_r)
{
  const int bid = blockIdx.x;
  const int part = bid & 3, chunk = (bid >> 2) & 31, b = (bid >> 7) & 7, dir = bid >> 10;
  const int tid = threadIdx.x, c = part * 256 + tid;
  const int bd = dir * 8 + b;

  const ushort* dblk = dir ? db_r : db_f;
  const ushort* ublk = dir ? ub_r : ub_f;
  const ushort* gblk = dir ? gb_r : gb_f;
  const ushort* dbc  = dir ? dbc_r : dbc_f;
  const float*  Alog = dir ? rA : fA;
  const float*  Dw   = dir ? rD : fD;
  ushort* ym         = dir ? ym_r : ym_f;

  __shared__ float Bs[CLS][16], Cs[CLS][16];   // 2 KB
  {
    const int s = tid >> 5, k = tid & 31;
#pragma unroll
    for (int p = 0; p < 2; ++p) {
      const int ss = s + p * 8;
      const int t = dir ? (Ln - 1 - (chunk * CLS + ss)) : (chunk * CLS + ss);
      const float val = bf2f(dbc[(size_t)(b * Ln + t) * 64 + 32 + k]);
      if (k < 16) Bs[ss][k] = val; else Cs[ss][k - 16] = val;
    }
  }
  __syncthreads();

  float a2[16];
  {
    const float4* Ar = (const float4*)(Alog + (size_t)c * 16);
#pragma unroll
    for (int g = 0; g < 4; ++g) {
      float4 av = Ar[g];
      a2[g*4+0] = -__expf(av.x) * 1.44269504f;
      a2[g*4+1] = -__expf(av.y) * 1.44269504f;
      a2[g*4+2] = -__expf(av.z) * 1.44269504f;
      a2[g*4+3] = -__expf(av.w) * 1.44269504f;
    }
  }
  const float Dc = Dw[c];

  const int sc = dir ? (31 - chunk) : chunk;
  const size_t blkBase = (((size_t)(b * 32 + sc)) * 1024 + c) * 16;
  const ushort8v dv0 = *(const ushort8v*)(dblk + blkBase);
  const ushort8v dv1 = *(const ushort8v*)(dblk + blkBase + 8);
  const ushort8v uv0 = *(const ushort8v*)(ublk + blkBase);
  const ushort8v uv1 = *(const ushort8v*)(ublk + blkBase + 8);
  const ushort8v gv0 = *(const ushort8v*)(gblk + blkBase);
  const ushort8v gv1 = *(const ushort8v*)(gblk + blkBase + 8);

  float h[16];
#pragma unroll
  for (int g = 0; g < 4; ++g) {
    const size_t o = ((size_t)g * 16 * NCH + (size_t)bd * NCH + chunk) * 1024 + c;
    const ushort4 hv = hin[o];
    h[g*4+0] = bf2f(hv.x); h[g*4+1] = bf2f(hv.y);
    h[g*4+2] = bf2f(hv.z); h[g*4+3] = bf2f(hv.w);
  }

  const int t0 = dir ? (Ln - 1 - chunk * CLS) : (chunk * CLS);
  const int stp = (dir ? -1 : 1) * DI;
  ushort* ymp = ym + (size_t)(b * Ln + t0) * DI + c;

  if (!dir) {
#pragma unroll
    for (int s = 0; s < CLS; ++s) SCAN3_STEP(s, s)
  } else {
#pragma unroll
    for (int s = 0; s < CLS; ++s) SCAN3_STEP(s, 15 - s)
  }
}

// ---------------------------------------------------------------------------
// LayerNorm over 512 cols of (a+b). One block per row.
// ---------------------------------------------------------------------------
template<int OUTF32>
__global__ __launch_bounds__(256)
void ln_k(const ushort* __restrict__ a, const ushort* __restrict__ b,
          const float* __restrict__ g, const float* __restrict__ bb,
          void* __restrict__ outv)
{
  const int row = blockIdx.x, tid = threadIdx.x;
  const size_t base = (size_t)row * DM;
  float v0 = bf2f(a[base + tid]) + bf2f(b[base + tid]);
  float v1 = bf2f(a[base + tid + 256]) + bf2f(b[base + tid + 256]);
  float s1 = v0 + v1, s2 = v0 * v0 + v1 * v1;
  for (int o = 32; o; o >>= 1) { s1 += __shfl_down(s1, o); s2 += __shfl_down(s2, o); }
  __shared__ float l1[4], l2[4];
  const int wv = tid >> 6, ln = tid & 63;
  if (ln == 0) { l1[wv] = s1; l2[wv] = s2; }
  __syncthreads();
  const float t1 = l1[0] + l1[1] + l1[2] + l1[3];
  const float t2 = l2[0] + l2[1] + l2[2] + l2[3];
  const float mean = t1 * (1.f / 512.f);
  const float var = t2 * (1.f / 512.f) - mean * mean;
  const float rs = rsqrtf(var + 1e-5f);
  const float o0 = (v0 - mean) * rs * g[tid] + bb[tid];
  const float o1 = (v1 - mean) * rs * g[tid + 256] + bb[tid + 256];
  if (OUTF32) {
    ((float*)outv)[base + tid] = o0;
    ((float*)outv)[base + tid + 256] = o1;
  } else {
    ((ushort*)outv)[base + tid] = f2bf(o0);
    ((ushort*)outv)[base + tid + 256] = f2bf(o1);
  }
}

// ---------------------------------------------------------------------------
extern "C" void kernel_launch(void* const* d_in, const int* in_sizes, int n_in,
                              void* d_out, int out_size, void* d_ws, size_t ws_size,
                              hipStream_t stream)
{
  const float* x        = (const float*)d_in[0];
  const float* f_in_w   = (const float*)d_in[1];
  const float* f_conv_w = (const float*)d_in[2];
  const float* f_conv_b = (const float*)d_in[3];
  const float* f_xproj  = (const float*)d_in[4];
  const float* f_dt_w   = (const float*)d_in[5];
  const float* f_dt_b   = (const float*)d_in[6];
  const float* f_A_log  = (const float*)d_in[7];
  const float* f_D      = (const float*)d_in[8];
  const float* f_out_w  = (const float*)d_in[9];
  const float* r_in_w   = (const float*)d_in[10];
  const float* r_conv_w = (const float*)d_in[11];
  const float* r_conv_b = (const float*)d_in[12];
  const float* r_xproj  = (const float*)d_in[13];
  const float* r_dt_w   = (const float*)d_in[14];
  const float* r_dt_b   = (const float*)d_in[15];
  const float* r_A_log  = (const float*)d_in[16];
  const float* r_D      = (const float*)d_in[17];
  const float* r_out_w  = (const float*)d_in[18];
  const float* conv1_w  = (const float*)d_in[19];
  const float* conv1_b  = (const float*)d_in[20];
  const float* conv2_w  = (const float*)d_in[21];
  const float* conv2_b  = (const float*)d_in[22];
  const float* ln1_g    = (const float*)d_in[23];
  const float* ln1_b    = (const float*)d_in[24];
  const float* ln2_g    = (const float*)d_in[25];
  const float* ln2_b    = (const float*)d_in[26];

  char* ws = (char*)d_ws;
  size_t off = 0;
  auto alloc = [&](size_t bytes) -> void* {
    void* p = ws + off;
    off += (bytes + 255) & ~(size_t)255;
    return p;
  };
  ushort* x_b     = (ushort*)alloc((size_t)Mtok * DM * 2);
  ushort* f_inw_b = (ushort*)alloc((size_t)2 * DI * DM * 2);
  ushort* r_inw_b = (ushort*)alloc((size_t)2 * DI * DM * 2);
  ushort* f_xp_b  = (ushort*)alloc((size_t)64 * DI * 2);
  ushort* r_xp_b  = (ushort*)alloc((size_t)64 * DI * 2);
  ushort* f_dtw_b = (ushort*)alloc((size_t)DI * 32 * 2);
  ushort* r_dtw_b = (ushort*)alloc((size_t)DI * 32 * 2);
  ushort* f_ow_b  = (ushort*)alloc((size_t)DM * DI * 2);
  ushort* r_ow_b  = (ushort*)alloc((size_t)DM * DI * 2);
  ushort* c1w_b   = (ushort*)alloc((size_t)DFF * DM * 2);
  ushort* c2w_b   = (ushort*)alloc((size_t)DM * DFF * 2);
  ushort* xz_f    = (ushort*)alloc((size_t)Mtok * 2048 * 2);
  ushort* xz_r    = (ushort*)alloc((size_t)Mtok * 2048 * 2);
  ushort* u_f     = (ushort*)alloc((size_t)Mtok * DI * 2);
  ushort* u_r     = (ushort*)alloc((size_t)Mtok * DI * 2);
  ushort* ub_f    = (ushort*)alloc((size_t)Mtok * DI * 2);
  ushort* ub_r    = (ushort*)alloc((size_t)Mtok * DI * 2);
  ushort* gb_f    = (ushort*)alloc((size_t)Mtok * DI * 2);
  ushort* gb_r    = (ushort*)alloc((size_t)Mtok * DI * 2);
  ushort* dbc_f   = (ushort*)alloc((size_t)Mtok * 64 * 2);
  ushort* dbc_r   = (ushort*)alloc((size_t)Mtok * 64 * 2);
  ushort* db_f    = (ushort*)alloc((size_t)Mtok * DI * 2);
  ushort* db_r    = (ushort*)alloc((size_t)Mtok * DI * 2);
  ushort* ym_f    = (ushort*)alloc((size_t)Mtok * DI * 2);
  ushort* ym_r    = (ushort*)alloc((size_t)Mtok * DI * 2);
  ushort* mo      = (ushort*)alloc((size_t)Mtok * DM * 2);
  ushort* x1      = (ushort*)alloc((size_t)Mtok * DM * 2);
  ushort* h1b     = (ushort*)alloc((size_t)Mtok * DFF * 2);
  ushort* y2      = (ushort*)alloc((size_t)Mtok * DM * 2);
  ushort4* hloc   = (ushort4*)alloc((size_t)4 * 16 * NCH * 1024 * 8);
  float*  Sa      = (float*)alloc((size_t)16 * NCH * 1024 * 4);
  (void)ws_size; (void)in_sizes; (void)n_in; (void)out_size;

  // 0. fp32 -> bf16 conversion (one launch)
  {
    CvtTab tb;
    int blk = 0, ji = 0;
    auto add = [&](const float* s, ushort* d, int n) {
      tb.j[ji].src = s; tb.j[ji].dst = d; tb.j[ji].blk0 = blk; tb.j[ji]._pad = 0;
      blk += n / 2048; ++ji;
    };
    add(x,       x_b,     Mtok * DM);
    add(f_in_w,  f_inw_b, 2 * DI * DM);
    add(r_in_w,  r_inw_b, 2 * DI * DM);
    add(f_xproj, f_xp_b,  64 * DI);
    add(r_xproj, r_xp_b,  64 * DI);
    add(f_dt_w,  f_dtw_b, DI * 32);
    add(r_dt_w,  r_dtw_b, DI * 32);
    add(f_out_w, f_ow_b,  DM * DI);
    add(r_out_w, r_ow_b,  DM * DI);
    add(conv1_w, c1w_b,   DFF * DM);
    add(conv2_w, c2w_b,   DM * DFF);
    cvt_k<<<dim3(blk), 256, 0, stream>>>(tb, ji);
  }

  // 1. xz = x @ in_w.T (f/r z-batched), LDS GEMM 128x128
  gemm_lds<128, 128, 2, 2, 0, 0, 0><<<dim3(32, 16, 2), 256, 0, stream>>>(
      x_b, f_inw_b, xz_f, nullptr, x_b, r_inw_b, xz_r, nullptr,
      nullptr, nullptr, DM, DM, DM, 2048, 0, 0, 0);

  // 2. depthwise conv + silu: u row-major + blocked u/gz (coalesced stores)
  conv_k<<<dim3(512), 256, 0, stream>>>(
      xz_f, xz_r, f_conv_w, f_conv_b, r_conv_w, r_conv_b,
      u_f, u_r, ub_f, ub_r, gb_f, gb_r);

  // 3. fused xproj + dt: dbc B/C cols + blocked delta
  xproj_k<<<dim3(256, 1, 2), 256, 0, stream>>>(
      u_f, f_xp_b, dbc_f, u_r, r_xp_b, dbc_r,
      f_dtw_b, f_dt_b, r_dtw_b, r_dt_b, db_f, db_r);

  // 4. chunked scan: local -> compose (in-place hin) -> emit
  scan1_k<<<dim3(2048), 256, 0, stream>>>(
      db_f, db_r, ub_f, ub_r, dbc_f, dbc_r, f_A_log, r_A_log, hloc, Sa);
  scan2_k<<<dim3(256), 256, 0, stream>>>(hloc, Sa, f_A_log, r_A_log);
  scan3_k<<<dim3(2048), 256, 0, stream>>>(
      db_f, db_r, ub_f, ub_r, dbc_f, dbc_r, gb_f, gb_r,
      f_A_log, f_D, r_A_log, r_D, hloc, ym_f, ym_r);

  // 5. mo = ym_f @ f_out_w.T + ym_r @ r_out_w.T, LDS GEMM 64x64 dual-K
  gemm_lds<64, 64, 2, 2, 0, 0, 1><<<dim3(64, 8, 1), 256, 0, stream>>>(
      ym_f, f_ow_b, mo, nullptr, nullptr, nullptr, nullptr, nullptr,
      ym_r, r_ow_b, DI, DI, DI, DM, DI, DI, DI);

  // 6. x1 = LN(x + mo)
  ln_k<0><<<dim3(Mtok), 256, 0, stream>>>(x_b, mo, ln1_g, ln1_b, x1);

  // 7. h1 = fast_gelu(x1 @ conv1_w.T + b1), LDS GEMM 128x128
  gemm_lds<128, 128, 2, 2, 3, 0, 0><<<dim3(32, 16, 1), 256, 0, stream>>>(
      x1, c1w_b, h1b, conv1_b, nullptr, nullptr, nullptr, nullptr,
      nullptr, nullptr, DM, DM, DM, DFF, 0, 0, 0);

  // 8. y2 = h1 @ conv2_w.T + b2, LDS GEMM 64x64
  gemm_lds<64, 64, 2, 2, 1, 0, 0><<<dim3(64, 8, 1), 256, 0, stream>>>(
      h1b, c2w_b, y2, conv2_b, nullptr, nullptr, nullptr, nullptr,
      nullptr, nullptr, DFF, DFF, DFF, DM, 0, 0, 0);

  // 9. out = LN(x1 + y2) -> fp32
  ln_k<1><<<dim3(Mtok), 256, 0, stream>>>(x1, y2, ln2_g, ln2_b, (float*)d_out);
}